// Round 6
// baseline (515.503 us; speedup 1.0000x reference)
//
#include <hip/hip_runtime.h>
#include <math.h>

// TrxMeanEncoder fused kernel for MI355X (gfx950) — round 6.
//
// out[b] = concat( hist(mcc[b])/1024  (W_mcc = I, folded),
//                  hist(trx[b])/1024  (W_trx = I, folded),
//                  mean_{t<L} log1p(|a|)*sign(a) )
//
// R1/R2/R4/R5 are all ~80us regardless of VALU load, occupancy, barriers,
// prefetch, or LDS banking -> the per-CU DS pipe executing the histogram
// update instructions is saturated (~1.5 cyc/update, invariant to conflict
// shaping). Update count per pipe is the only lever left.
//
// Round-6: SPLIT ACROSS PIPES. mcc (1024 upd/row) stays on LDS atomics;
// trx (1024 upd/row) goes to GLOBAL float atomics straight into d_out
// (TCC/L2 atomic units — currently idle). d_out is zeroed first via a
// capture-safe hipMemsetAsync node; trx counts accumulate as exact 2^-10
// increments (k/1024 is always exact in fp32). mcc + means columns are
// overwritten by normal stores afterwards.

constexpr int kB       = 16384;
constexpr int kT       = 1024;
constexpr int kVmcc    = 400;
constexpr int kNout    = 501;
constexpr int kThreads = 256;   // 4 waves, 1 row per wave (R2 structure)
constexpr int kHStride = 512;   // u32 words per wave histogram (400 used)

__global__ __launch_bounds__(kThreads) void trx_mean_encoder(
    const int* __restrict__ mcc, const int* __restrict__ trx,
    const float* __restrict__ amount, const int* __restrict__ seq_lens,
    float* __restrict__ out)
{
  __shared__ unsigned int hist[4 * kHStride];  // 8 KB (one slice per wave)

  const int tid  = threadIdx.x;
  const int wid  = tid >> 6;
  const int lane = tid & 63;
  const int row  = blockIdx.x * 4 + wid;

  unsigned int* h = hist + wid * kHStride;  // mcc bins [0,400)

  // Zero this wave's mcc histogram: 2x ds_write_b128 per lane (same-wave DS
  // ordering guarantees zeros land before our atomics; validated R2).
  const uint4 z = make_uint4(0u, 0u, 0u, 0u);
  reinterpret_cast<uint4*>(h)[lane]      = z;
  reinterpret_cast<uint4*>(h)[lane + 64] = z;

  const size_t  rowoff = (size_t)row * kT;
  const int4*   m4p = reinterpret_cast<const int4*>(mcc + rowoff);
  const int4*   t4p = reinterpret_cast<const int4*>(trx + rowoff);
  const float4* a4p = reinterpret_cast<const float4*>(amount + rowoff);

  // 16 tokens/lane: 12 coalesced 16B loads, issued up front.
  int4 m[4], t[4]; float4 a[4];
#pragma unroll
  for (int k = 0; k < 4; ++k) {
    m[k] = m4p[lane + 64 * k];
    t[k] = t4p[lane + 64 * k];
    a[k] = a4p[lane + 64 * k];
  }
  const int L = seq_lens[row];  // wave-uniform -> scalar load

  float* orow = out + (size_t)row * kNout;
  float* otrx = orow + kVmcc;              // trx region [400,500): atomics only
  constexpr float kInc = 1.0f / 1024.0f;   // exact power of two
  constexpr float kLn2 = 0.69314718055994531f;

  float s = 0.0f;
#pragma unroll
  for (int k = 0; k < 4; ++k) {
    // trx -> TCC/L2 atomic pipe (fire-and-forget, no return value).
    atomicAdd(&otrx[t[k].x], kInc);
    atomicAdd(&otrx[t[k].y], kInc);
    atomicAdd(&otrx[t[k].z], kInc);
    atomicAdd(&otrx[t[k].w], kInc);

    // mcc -> LDS/DS atomic pipe.
    atomicAdd(&h[m[k].x], 1u);
    atomicAdd(&h[m[k].y], 1u);
    atomicAdd(&h[m[k].z], 1u);
    atomicAdd(&h[m[k].w], 1u);

    // LogScaler + ragged mask on the (idle) VALU/transcendental pipes.
    const int   base  = 4 * (lane + 64 * k);
    const float av[4] = {a[k].x, a[k].y, a[k].z, a[k].w};
#pragma unroll
    for (int j = 0; j < 4; ++j) {
      const float x = av[j];
      const float v = __log2f(1.0f + fabsf(x)) * kLn2;  // log1p(|x|)
      s += (base + j < L) ? copysignf(v, x) : 0.0f;
    }
  }

  // Wave-wide butterfly sum.
#pragma unroll
  for (int off = 32; off; off >>= 1) s += __shfl_xor(s, off, 64);

  // Drain this wave's DS atomics before reading mcc counts back.
  asm volatile("s_waitcnt lgkmcnt(0)" ::: "memory");

  const float inv_t = 1.0f / (float)kT;
  // mcc readback: bin v = lane + 64k -> stride-1 LDS reads (2-way, free),
  // fully coalesced dword stores.
#pragma unroll
  for (int k = 0; k < 7; ++k) {
    const int v = lane + 64 * k;
    if (v < kVmcc) orow[v] = (float)h[v] * inv_t;
  }
  if (lane == 0) orow[kNout - 1] = s / (float)L;
}

extern "C" void kernel_launch(void* const* d_in, const int* in_sizes, int n_in,
                              void* d_out, int out_size, void* d_ws, size_t ws_size,
                              hipStream_t stream) {
  const int*   mcc      = (const int*)d_in[0];
  const int*   trx      = (const int*)d_in[1];
  const float* amount   = (const float*)d_in[2];
  const int*   seq_lens = (const int*)d_in[3];
  // d_in[4] (W_mcc) and d_in[5] (W_trx) are identity matrices -> folded.
  (void)in_sizes; (void)n_in; (void)d_ws; (void)ws_size;

  // Zero d_out (capture-safe stream memset node): trx columns accumulate
  // global atomics; mcc/means columns are overwritten by normal stores.
  hipMemsetAsync(d_out, 0, (size_t)out_size * sizeof(float), stream);

  trx_mean_encoder<<<dim3(kB / 4), dim3(kThreads), 0, stream>>>(
      mcc, trx, amount, seq_lens, (float*)d_out);
}

// Round 7
// 213.970 us; speedup vs baseline: 2.4092x; 2.4092x over previous
//
#include <hip/hip_runtime.h>
#include <math.h>

// TrxMeanEncoder fused kernel for MI355X (gfx950) — round 7: NO ATOMICS.
//
// out[b] = concat( hist(mcc[b])/1024, hist(trx[b])/1024  (W = I, folded),
//                  mean_{t<L} log1p(|a|)*sign(a) )
//
// R1-R5 established: LDS atomicAdd retires ~1 lane-update/1.4 cyc serially,
// invariant to banking/occupancy/VALU -> any atomic design floors ~55-77us.
// R6: global atomics are 5x worse (L2 thrash, 10x write amplification).
//
// Round-7 design: one WAVE per row (64-thread block), per-LANE private
// u8-packed histograms in LDS (region-major: lane r owns words
// [128r,128r+128), bins unified v in [0,500): word v>>2, byte v&3).
//  - updates: plain ds_read_b32/ds_write_b32 RMW (bank-parallel, ~6-10 cyc
//    vs ~90 for atomic). Correctness: per-wave DS ops execute IN ORDER in
//    HW; mcc/trx RMW pairs interleave (disjoint word ranges 0-99 / 100-124)
//    for depth-2 latency overlap. Max per-lane count = 16 tokens <= 255.
//  - merge: contiguous conflict-free ds_read_b128 (1 KB/instr = 2 regions);
//    u8->u16-SIMD widening accumulate (32 iters, max 512/u16); one
//    shfl_xor(32) folds even/odd region halves; lanes 0..31 store 16 bins.
//  - no barriers, no atomics anywhere.

constexpr int kB    = 16384;
constexpr int kT    = 1024;
constexpr int kNout = 501;

// 16B store with only 4B alignment guaranteed (row stride 2004 B).
struct __attribute__((aligned(4))) f4a { float x, y, z, w; };

__global__ __launch_bounds__(64) void trx_mean_encoder(
    const int* __restrict__ mcc, const int* __restrict__ trx,
    const float* __restrict__ amount, const int* __restrict__ seq_lens,
    float* __restrict__ out)
{
  __shared__ unsigned int h[64 * 128];  // 32 KB: lane r's region = h[128r..128r+127]

  const int lane = threadIdx.x;  // block = 1 wave
  const int row  = blockIdx.x;

  // Zero all 32 KB: 32x contiguous ds_write_b128 (conflict-free).
  uint4* h4 = reinterpret_cast<uint4*>(h);
  const uint4 z = make_uint4(0u, 0u, 0u, 0u);
#pragma unroll
  for (int i = 0; i < 32; ++i) h4[i * 64 + lane] = z;

  const size_t  rowoff = (size_t)row * kT;
  const int4*   m4p = reinterpret_cast<const int4*>(mcc + rowoff);
  const int4*   t4p = reinterpret_cast<const int4*>(trx + rowoff);
  const float4* a4p = reinterpret_cast<const float4*>(amount + rowoff);

  // 16 tokens/lane: 12 coalesced 16B loads, issued up front.
  int4 m[4], t[4]; float4 a[4];
#pragma unroll
  for (int k = 0; k < 4; ++k) {
    m[k] = m4p[lane + 64 * k];
    t[k] = t4p[lane + 64 * k];
    a[k] = a4p[lane + 64 * k];
  }
  const int L = seq_lens[row];  // wave-uniform

  unsigned int* hr = h + lane * 128;  // this lane's private region
  constexpr float kLn2 = 0.69314718055994531f;
  float s = 0.0f;

#pragma unroll
  for (int k = 0; k < 4; ++k) {
    const int   mv[4] = {m[k].x, m[k].y, m[k].z, m[k].w};
    const int   tv[4] = {t[k].x + 400, t[k].y + 400, t[k].z + 400, t[k].w + 400};
    const float av[4] = {a[k].x, a[k].y, a[k].z, a[k].w};
#pragma unroll
    for (int j = 0; j < 4; ++j) {
      const int vm = mv[j], vt = tv[j];
      // Interleaved RMW pair: vm-word in [0,100), vt-word in [100,125) —
      // disjoint, so read-read-write-write is safe; HW DS order handles
      // same-lane duplicate bins across iterations.
      const unsigned um = hr[vm >> 2];
      const unsigned ut = hr[vt >> 2];
      hr[vm >> 2] = um + (1u << ((vm & 3) * 8));
      hr[vt >> 2] = ut + (1u << ((vt & 3) * 8));

      // LogScaler + ragged mask (VALU work fills the DS wait shadows).
      const float x = av[j];
      const float v = __log2f(1.0f + fabsf(x)) * kLn2;  // log1p(|x|)
      s += (4 * (lane + 64 * k) + j < L) ? copysignf(v, x) : 0.0f;
    }
  }

  // Wave-wide butterfly sum of the masked log values.
#pragma unroll
  for (int off = 32; off; off >>= 1) s += __shfl_xor(s, off, 64);

  // ---- Merge: sum the 64 private regions, conflict-free contiguous reads.
  // Instruction i: lanes 0..31 read region 2i, lanes 32..63 read region
  // 2i+1; lane's uint4 = words [4q,4q+3] (q = lane&31) = bins [16q,16q+16).
  unsigned aL0 = 0, aL1 = 0, aL2 = 0, aL3 = 0;  // u16-SIMD: bytes 0,2
  unsigned aH0 = 0, aH1 = 0, aH2 = 0, aH3 = 0;  // u16-SIMD: bytes 1,3
#pragma unroll
  for (int i = 0; i < 32; ++i) {
    const uint4 c = h4[i * 64 + lane];
    aL0 += c.x & 0x00FF00FFu;  aH0 += (c.x >> 8) & 0x00FF00FFu;
    aL1 += c.y & 0x00FF00FFu;  aH1 += (c.y >> 8) & 0x00FF00FFu;
    aL2 += c.z & 0x00FF00FFu;  aH2 += (c.z >> 8) & 0x00FF00FFu;
    aL3 += c.w & 0x00FF00FFu;  aH3 += (c.w >> 8) & 0x00FF00FFu;
  }
  // Fold even-region half (lanes 0..31) with odd-region half (lanes 32..63).
  aL0 += __shfl_xor(aL0, 32, 64);  aH0 += __shfl_xor(aH0, 32, 64);
  aL1 += __shfl_xor(aL1, 32, 64);  aH1 += __shfl_xor(aH1, 32, 64);
  aL2 += __shfl_xor(aL2, 32, 64);  aH2 += __shfl_xor(aH2, 32, 64);
  aL3 += __shfl_xor(aL3, 32, 64);  aH3 += __shfl_xor(aH3, 32, 64);

  float* orow = out + (size_t)row * kNout;
  const float inv_t = 1.0f / (float)kT;

  if (lane < 32) {
    const int b0 = lane * 16;  // this lane's 16 bins: [b0, b0+16)
    const unsigned lo[4] = {aL0, aL1, aL2, aL3};
    const unsigned hi[4] = {aH0, aH1, aH2, aH3};
#pragma unroll
    for (int j = 0; j < 4; ++j) {
      const int bb = b0 + 4 * j;
      if (bb < 500) {  // bins 500..511 are padding
        f4a o;
        o.x = (float)(lo[j] & 0xFFFFu) * inv_t;  // bin bb+0
        o.y = (float)(hi[j] & 0xFFFFu) * inv_t;  // bin bb+1
        o.z = (float)(lo[j] >> 16)     * inv_t;  // bin bb+2
        o.w = (float)(hi[j] >> 16)     * inv_t;  // bin bb+3
        *reinterpret_cast<f4a*>(orow + bb) = o;
      }
    }
  }
  if (lane == 0) orow[kNout - 1] = s / (float)L;
}

extern "C" void kernel_launch(void* const* d_in, const int* in_sizes, int n_in,
                              void* d_out, int out_size, void* d_ws, size_t ws_size,
                              hipStream_t stream) {
  const int*   mcc      = (const int*)d_in[0];
  const int*   trx      = (const int*)d_in[1];
  const float* amount   = (const float*)d_in[2];
  const int*   seq_lens = (const int*)d_in[3];
  // d_in[4] (W_mcc) and d_in[5] (W_trx) are identity matrices -> folded.
  (void)in_sizes; (void)n_in; (void)d_ws; (void)ws_size; (void)out_size;

  trx_mean_encoder<<<dim3(kB), dim3(64), 0, stream>>>(
      mcc, trx, amount, seq_lens, (float*)d_out);
}